// Round 1
// baseline (593.751 us; speedup 1.0000x reference)
//
#include <hip/hip_runtime.h>
#include <hip/hip_bf16.h>

// ---------------------------------------------------------------------------
// Spatial_AttLayer on MI355X (gfx950), bf16 MFMA, fully fused main kernel.
//
// This revision targets the latency/occupancy bottleneck (prev: 1 WG/CU,
// 140 KB LDS, all pipes <20% busy). Changes vs previous version:
//   * tile = 2 t's (64 cols) per WG instead of 4 (Fl 67.6 KB -> 33.8 KB)
//   * Wo is NOT staged through LDS: GEMM3 A-fragments are read directly
//     from global (L2-resident, 8x1 wave grid -> no duplicate A reads)
//   * LDS total 52,224 B -> 3 WGs/CU (24 waves/CU), __launch_bounds__(512,6)
//   * WvP/WoP workspace layouts slimmed (no k-padding needed for global reads)
// Chain per WG (n, 2 t's; cols col = t*32+vp, vp padded 25->32, pads zero):
//   Vm = Wv@F + bv        (MFMA, M=64  K=256 N=64)
//   Zh = Vm@attn[h]       (MFMA, M=64  K=32  N=64, per head)
//   Out = sum_h Wo_h@Zh + bo + F   (MFMA, M=256 K=64/head N=64)
// Residual+bias folded into GEMM3 accumulator init.
// ---------------------------------------------------------------------------

typedef __attribute__((ext_vector_type(8))) short short8;
typedef __attribute__((ext_vector_type(4))) short short4v;
typedef __attribute__((ext_vector_type(4))) float f4v;

static __device__ __forceinline__ unsigned short f2bf(float f) {
  union { float f; unsigned u; } v; v.f = f;
  unsigned r = v.u + 0x7fffu + ((v.u >> 16) & 1u);   // RNE
  return (unsigned short)(r >> 16);
}
static __device__ __forceinline__ float bf2f(unsigned short h) {
  union { unsigned u; float f; } v; v.u = ((unsigned)h) << 16;
  return v.f;
}

// ws layout (unsigned short units unless noted):
//   WvP   [64][256]        bf16                               16384 elems
//   WoP   [8][256][64]     bf16 (per-head image, no pad)     131072 elems
//   attnP [8][32][40]      bf16 (B-layout [vp][u], zero-pad)  10240 elems
//   qkP   [2][8][64][25]   f32 (q then k)                     25600 floats

// ---------------------------------------------------------------------------
// Kernel 1a: q/k 1x1 conv (one dot per thread) + weight conversions.
__global__ void k_qk_conv(const float* __restrict__ tf,
                          const float* __restrict__ Wq, const float* __restrict__ bq,
                          const float* __restrict__ Wk, const float* __restrict__ bk,
                          const float* __restrict__ Wv, const float* __restrict__ Wo,
                          unsigned short* __restrict__ WvP,
                          unsigned short* __restrict__ WoP,
                          float* __restrict__ qkP)
{
  __shared__ float tfl[12800];
  const int b = blockIdx.x, tid = threadIdx.x;
  if (b < 100) {
    for (int i = tid; i < 12800; i += 256) tfl[i] = tf[i];
    __syncthreads();
    int idx = b * 256 + tid;                    // 0..25599
    int isK = idx >= 12800;
    int j = isK ? idx - 12800 : idx;
    int g = j / 25, u = j - 25 * g;             // g: 0..511
    const float* wrow = (isK ? Wk : Wq) + g * 512;
    float s = (isK ? bk : bq)[g];
    for (int i = 0; i < 512; ++i) s += wrow[i] * tfl[i * 25 + u];
    qkP[idx] = s;
  } else {
    int cb = b - 100;                           // 0..63
    for (int i = cb * 256 + tid; i < 16384; i += 64 * 256) {
      WvP[i] = f2bf(Wv[i]);                     // [c][k] row-major, same as Wv
    }
    for (int i = cb * 256 + tid; i < 131072; i += 64 * 256) {
      int hh = i >> 14, rr = i & 16383;         // h, then [o][k]
      int o = rr >> 6, kk = rr & 63;
      WoP[i] = f2bf(Wo[o * 512 + hh * 64 + kk]);
    }
  }
}

// ---------------------------------------------------------------------------
// Kernel 1b: energy + softmax per head -> attnP (zero-padded B-layout).
__global__ void k_attn(const float* __restrict__ qkP,
                       unsigned short* __restrict__ attnP)
{
  __shared__ float ql[1600], kl[1600], attl[625];
  const int h = blockIdx.x, tid = threadIdx.x;
  for (int i = tid; i < 1600; i += 256) {
    ql[i] = qkP[h * 1600 + i];
    kl[i] = qkP[12800 + h * 1600 + i];
  }
  __syncthreads();
  if (tid < 25) {
    int u = tid;
    float e[25];
    float mx = -1e30f;
    #pragma unroll
    for (int v = 0; v < 25; ++v) {
      float s = 0.f;
      #pragma unroll
      for (int r = 0; r < 64; ++r) s += ql[r * 25 + u] * kl[r * 25 + v];
      s *= 0.125f;                              // 1/sqrt(64)
      e[v] = s;
      mx = fmaxf(mx, s);
    }
    float den = 0.f;
    #pragma unroll
    for (int v = 0; v < 25; ++v) { e[v] = __expf(e[v] - mx); den += e[v]; }
    float inv = 1.f / den;
    #pragma unroll
    for (int v = 0; v < 25; ++v) attl[u * 25 + v] = e[v] * inv;
  }
  __syncthreads();
  // attnP[h][vp][u] = attn[u][vp]; zero where u>=25 or vp>=25
  for (int i = tid; i < 1280; i += 256) {
    int vp = i / 40, u = i - 40 * vp;
    attnP[h * 1280 + i] =
        (vp < 25 && u < 25) ? f2bf(attl[u * 25 + vp]) : (unsigned short)0;
  }
}

// ---------------------------------------------------------------------------
// Main fused kernel. 512 threads (8 waves), 3 WGs/CU (LDS 52224 B).
// LDS: Fl [64][264] @0 | Vl [64][72] @33792 | Zl [64][72] @43008
__launch_bounds__(512, 6)
__global__ void k_main(const float* __restrict__ feature,
                       const float* __restrict__ bv,
                       const float* __restrict__ bo,
                       const unsigned short* __restrict__ WvP,
                       const unsigned short* __restrict__ WoP,
                       const unsigned short* __restrict__ attnP,
                       float* __restrict__ out)
{
  extern __shared__ char smem[];
  unsigned short* Fl = (unsigned short*)smem;            // [64 cols][264]
  unsigned short* Vl = (unsigned short*)(smem + 33792);  // [64 rows][72]
  unsigned short* Zl = (unsigned short*)(smem + 43008);  // [64 cols][72]

  const int tid  = threadIdx.x;
  const int wave = tid >> 6;
  const int lane = tid & 63;
  const int quad = lane >> 4;
  const int l16  = lane & 15;
  const int n  = blockIdx.x >> 9;
  const int tb = blockIdx.x & 511;
  const int t0 = tb * 2;

  // --- zero F region (vp pads must be exactly 0; garbage could be NaN) ---
  {
    short8 z = {0, 0, 0, 0, 0, 0, 0, 0};
    short8* fz = (short8*)smem;
    for (int i = tid; i < 2112; i += 512) fz[i] = z;
  }
  __syncthreads();

  // --- stage F: fp32 -> bf16, Fl[col=(t*32+vp)][cin] ---
  {
    const int c = tid >> 1, p = tid & 1;
    const float2* src = reinterpret_cast<const float2*>(
        feature + ((size_t)(n * 256 + c) * 1024 + t0) * 25);
    for (int i = p; i < 25; i += 2) {
      float2 f = src[i];
      int j0 = 2 * i;
      {
        int j = j0;       int t = (j >= 25); int vp = j - 25 * t;
        Fl[(t * 32 + vp) * 264 + c] = f2bf(f.x);
      }
      {
        int j = j0 + 1;   int t = (j >= 25); int vp = j - 25 * t;
        Fl[(t * 32 + vp) * 264 + c] = f2bf(f.y);
      }
    }
  }
  __syncthreads();

  // --- GEMM3 accumulators, init with bias + residual. Wave grid 8x1:
  //     wave owns output rows wave*32..+32, all 64 cols.
  //     (C/D layout: row = quad*4+reg, col = l16 within each 16x16 tile) ---
  f4v acc[2][4];
  #pragma unroll
  for (int mi = 0; mi < 2; ++mi) {
    #pragma unroll
    for (int r = 0; r < 4; ++r) {
      int o = wave * 32 + mi * 16 + quad * 4 + r;
      float bor = bo[o];
      #pragma unroll
      for (int ni = 0; ni < 4; ++ni) {
        int colb = ni * 16 + l16;
        acc[mi][ni][r] = bor + bf2f(Fl[colb * 264 + o]);
      }
    }
  }

  // --- GEMM1: Vm = Wv@F + bv. Wave w: Mtile=w&3, col-half=w>>2.
  //     A fragments read directly from global WvP (L2-resident). ---
  {
    const int mt1 = wave & 3, nh1 = wave >> 2;
    f4v accv[2];
    #pragma unroll
    for (int ni = 0; ni < 2; ++ni) {
      #pragma unroll
      for (int r = 0; r < 4; ++r) accv[ni][r] = bv[mt1 * 16 + quad * 4 + r];
    }
    #pragma unroll
    for (int ks = 0; ks < 8; ++ks) {
      short8 a = *reinterpret_cast<const short8*>(
          WvP + (mt1 * 16 + l16) * 256 + ks * 32 + quad * 8);
      #pragma unroll
      for (int ni = 0; ni < 2; ++ni) {
        int colb = (2 * nh1 + ni) * 16 + l16;
        short8 b = *reinterpret_cast<const short8*>(
            &Fl[colb * 264 + ks * 32 + quad * 8]);
        accv[ni] = __builtin_amdgcn_mfma_f32_16x16x32_bf16(a, b, accv[ni], 0, 0, 0);
      }
    }
    #pragma unroll
    for (int ni = 0; ni < 2; ++ni) {
      int colb = (2 * nh1 + ni) * 16 + l16;
      #pragma unroll
      for (int r = 0; r < 4; ++r) {
        int c = mt1 * 16 + quad * 4 + r;
        Vl[c * 72 + colb] = f2bf(accv[ni][r]);
      }
    }
  }
  __syncthreads();

  // --- head loop: {GEMM2} barrier {GEMM3 (Wo direct from global)} barrier ---
  #pragma unroll 1
  for (int h = 0; h < 8; ++h) {
    // (1) GEMM2: Zh = Vm @ attn[h]. Wave w: A-row tile = w>>1, t = w&1.
    {
      const int am = wave >> 1;   // V row tile (16 rows)
      const int np = wave & 1;    // t index: cols np*32 .. np*32+31
      short8 a = *reinterpret_cast<const short8*>(
          &Vl[(am * 16 + l16) * 72 + np * 32 + quad * 8]);
      f4v accz[2];
      #pragma unroll
      for (int j = 0; j < 2; ++j) {
        f4v z = {0.f, 0.f, 0.f, 0.f};
        short8 b = *reinterpret_cast<const short8*>(
            attnP + h * 1280 + (j * 16 + l16) * 40 + quad * 8);
        accz[j] = __builtin_amdgcn_mfma_f32_16x16x32_bf16(a, b, z, 0, 0, 0);
      }
      #pragma unroll
      for (int j = 0; j < 2; ++j) {
        int col = np * 32 + j * 16 + l16;
        int c0 = am * 16 + quad * 4;
        short4v zz;
        #pragma unroll
        for (int r = 0; r < 4; ++r) zz[r] = (short)f2bf(accz[j][r]);
        *reinterpret_cast<short4v*>(&Zl[col * 72 + c0]) = zz;
      }
    }
    __syncthreads();

    // (2) GEMM3: acc += Wo_h @ Zh  (K=64, 2 k-steps). A from global (L2).
    {
      const unsigned short* __restrict__ woh = WoP + h * 16384;
      #pragma unroll
      for (int ks = 0; ks < 2; ++ks) {
        short8 bfr[4], afr[2];
        #pragma unroll
        for (int ni = 0; ni < 4; ++ni)
          bfr[ni] = *reinterpret_cast<const short8*>(
              &Zl[(ni * 16 + l16) * 72 + ks * 32 + quad * 8]);
        #pragma unroll
        for (int mi = 0; mi < 2; ++mi)
          afr[mi] = *reinterpret_cast<const short8*>(
              woh + (wave * 32 + mi * 16 + l16) * 64 + ks * 32 + quad * 8);
        #pragma unroll
        for (int mi = 0; mi < 2; ++mi) {
          #pragma unroll
          for (int ni = 0; ni < 4; ++ni)
            acc[mi][ni] =
                __builtin_amdgcn_mfma_f32_16x16x32_bf16(afr[mi], bfr[ni], acc[mi][ni], 0, 0, 0);
        }
      }
    }
    __syncthreads();
  }

  // --- epilogue: store fp32, skip vp pads ---
  #pragma unroll
  for (int ni = 0; ni < 4; ++ni) {
    int colb = ni * 16 + l16;
    int t = colb >> 5, vp = colb & 31;
    if (vp < 25) {
      #pragma unroll
      for (int mi = 0; mi < 2; ++mi) {
        #pragma unroll
        for (int r = 0; r < 4; ++r) {
          int o = wave * 32 + mi * 16 + quad * 4 + r;
          out[((size_t)(n * 256 + o) * 1024 + (t0 + t)) * 25 + vp] = acc[mi][ni][r];
        }
      }
    }
  }
}

// ---------------------------------------------------------------------------
extern "C" void kernel_launch(void* const* d_in, const int* in_sizes, int n_in,
                              void* d_out, int out_size, void* d_ws, size_t ws_size,
                              hipStream_t stream)
{
  const float* feature = (const float*)d_in[0];
  const float* tf      = (const float*)d_in[1];
  const float* Wq      = (const float*)d_in[2];
  const float* bq      = (const float*)d_in[3];
  const float* Wk      = (const float*)d_in[4];
  const float* bk      = (const float*)d_in[5];
  const float* Wv      = (const float*)d_in[6];
  const float* bv      = (const float*)d_in[7];
  const float* Wo      = (const float*)d_in[8];
  const float* bo      = (const float*)d_in[9];
  float* out = (float*)d_out;

  unsigned short* WvP   = (unsigned short*)d_ws;        // 16384
  unsigned short* WoP   = WvP + 16384;                  // 131072
  unsigned short* attnP = WoP + 131072;                 // 10240
  float* qkP = (float*)(attnP + 10240);                 // 25600 floats

  hipLaunchKernelGGL(k_qk_conv, dim3(164), dim3(256), 0, stream,
                     tf, Wq, bq, Wk, bk, Wv, Wo, WvP, WoP, qkP);
  hipLaunchKernelGGL(k_attn, dim3(8), dim3(256), 0, stream, qkP, attnP);

  hipLaunchKernelGGL(k_main, dim3(4096), dim3(512), 52224, stream,
                     feature, bv, bo, WvP, WoP, attnP, out);
}

// Round 2
// 547.665 us; speedup vs baseline: 1.0842x; 1.0842x over previous
//
#include <hip/hip_runtime.h>
#include <hip/hip_bf16.h>

// ---------------------------------------------------------------------------
// Spatial_AttLayer on MI355X (gfx950), bf16 MFMA.
//
// Round-2 restructure: the per-head loop (18 barriers/WG, global Wo loads
// inside barrier sandwiches) is collapsed into two wide GEMM phases:
//   GEMM2: Z_cat = Vm @ [A_0|...|A_7]   (per t: M=64, N=256, K=32)  1 barrier
//   GEMM3: Out   = Wo @ Z_cat           (M=256, N=cols, K=512)      1 barrier
// Z row index k = h*64+c equals Wo's native column order, so WoP is a plain
// bf16 cast of Wo (no per-head repack). Z (64x520 bf16, 66.6 KB) overlays
// the dead Fl region; LDS total 75,776 B -> 2 WGs/CU.
// Barriers per WG: 3. All global fragment loads (Wv, attn, first Wo chunk)
// are issued ABOVE the barrier that precedes their use.
// Block mapping n = bid&7: each XCD keeps one batch image + Wo in its L2.
// ---------------------------------------------------------------------------

typedef __attribute__((ext_vector_type(8))) short short8;
typedef __attribute__((ext_vector_type(4))) short short4v;
typedef __attribute__((ext_vector_type(4))) float f4v;

static __device__ __forceinline__ unsigned short f2bf(float f) {
  union { float f; unsigned u; } v; v.f = f;
  unsigned r = v.u + 0x7fffu + ((v.u >> 16) & 1u);   // RNE
  return (unsigned short)(r >> 16);
}
static __device__ __forceinline__ float bf2f(unsigned short h) {
  union { unsigned u; float f; } v; v.u = ((unsigned)h) << 16;
  return v.f;
}

// ws layout (unsigned short units unless noted):
//   WvP   [64][256]        bf16                               16384 elems
//   WoP   [256][512]       bf16 (plain cast, native order)   131072 elems
//   attnP [8][32][40]      bf16 (B-layout [vp][u], zero-pad)  10240 elems
//   qkP   [2][8][64][25]   f32 (q then k)                     25600 floats

// ---------------------------------------------------------------------------
// Kernel 1a: q/k 1x1 conv (one dot per thread) + weight conversions.
__global__ void k_qk_conv(const float* __restrict__ tf,
                          const float* __restrict__ Wq, const float* __restrict__ bq,
                          const float* __restrict__ Wk, const float* __restrict__ bk,
                          const float* __restrict__ Wv, const float* __restrict__ Wo,
                          unsigned short* __restrict__ WvP,
                          unsigned short* __restrict__ WoP,
                          float* __restrict__ qkP)
{
  __shared__ float tfl[12800];
  const int b = blockIdx.x, tid = threadIdx.x;
  if (b < 100) {
    for (int i = tid; i < 12800; i += 256) tfl[i] = tf[i];
    __syncthreads();
    int idx = b * 256 + tid;                    // 0..25599
    int isK = idx >= 12800;
    int j = isK ? idx - 12800 : idx;
    int g = j / 25, u = j - 25 * g;             // g: 0..511
    const float* wrow = (isK ? Wk : Wq) + g * 512;
    float s = (isK ? bk : bq)[g];
    for (int i = 0; i < 512; ++i) s += wrow[i] * tfl[i * 25 + u];
    qkP[idx] = s;
  } else {
    int cb = b - 100;                           // 0..63
    for (int i = cb * 256 + tid; i < 16384; i += 64 * 256) {
      WvP[i] = f2bf(Wv[i]);                     // [c][k] row-major, same as Wv
    }
    for (int i = cb * 256 + tid; i < 131072; i += 64 * 256) {
      WoP[i] = f2bf(Wo[i]);                     // native [o][h*64+c] order
    }
  }
}

// ---------------------------------------------------------------------------
// Kernel 1b: energy + softmax per head -> attnP (zero-padded B-layout).
__global__ void k_attn(const float* __restrict__ qkP,
                       unsigned short* __restrict__ attnP)
{
  __shared__ float ql[1600], kl[1600], attl[625];
  const int h = blockIdx.x, tid = threadIdx.x;
  for (int i = tid; i < 1600; i += 256) {
    ql[i] = qkP[h * 1600 + i];
    kl[i] = qkP[12800 + h * 1600 + i];
  }
  __syncthreads();
  if (tid < 25) {
    int u = tid;
    float e[25];
    float mx = -1e30f;
    #pragma unroll
    for (int v = 0; v < 25; ++v) {
      float s = 0.f;
      #pragma unroll
      for (int r = 0; r < 64; ++r) s += ql[r * 25 + u] * kl[r * 25 + v];
      s *= 0.125f;                              // 1/sqrt(64)
      e[v] = s;
      mx = fmaxf(mx, s);
    }
    float den = 0.f;
    #pragma unroll
    for (int v = 0; v < 25; ++v) { e[v] = __expf(e[v] - mx); den += e[v]; }
    float inv = 1.f / den;
    #pragma unroll
    for (int v = 0; v < 25; ++v) attl[u * 25 + v] = e[v] * inv;
  }
  __syncthreads();
  // attnP[h][vp][u] = attn[u][vp]; zero where u>=25 or vp>=25
  for (int i = tid; i < 1280; i += 256) {
    int vp = i / 40, u = i - 40 * vp;
    attnP[h * 1280 + i] =
        (vp < 25 && u < 25) ? f2bf(attl[u * 25 + vp]) : (unsigned short)0;
  }
}

// ---------------------------------------------------------------------------
// Main fused kernel. 512 threads (8 waves), 2 WGs/CU (LDS 75776 B).
// LDS: phase A: Fl [64 cols][264] @0 (33792 B)
//      phase B: Zl [64 cols][520] @0 (66560 B, overlays dead Fl)
//      both:    Vl [64 c][72]     @66560 (9216 B)
__launch_bounds__(512, 4)
__global__ void k_main(const float* __restrict__ feature,
                       const float* __restrict__ bv,
                       const float* __restrict__ bo,
                       const unsigned short* __restrict__ WvP,
                       const unsigned short* __restrict__ WoP,
                       const unsigned short* __restrict__ attnP,
                       float* __restrict__ out)
{
  extern __shared__ char smem[];
  unsigned short* Fl = (unsigned short*)smem;            // [64][264] phase A
  unsigned short* Zl = (unsigned short*)smem;            // [64][520] phase B
  unsigned short* Vl = (unsigned short*)(smem + 66560);  // [64][72]

  const int tid  = threadIdx.x;
  const int wave = tid >> 6;
  const int lane = tid & 63;
  const int quad = lane >> 4;
  const int l16  = lane & 15;
  const int n  = blockIdx.x & 7;          // one batch image per XCD
  const int tb = blockIdx.x >> 3;         // 0..511
  const int t0 = tb * 2;

  // --- zero ONLY the pad columns of Fl (vp 25..31, both t): 14 cols x 33 v8
  if (tid < 462) {
    short8 z = {0, 0, 0, 0, 0, 0, 0, 0};
    int pc = tid / 33, off = tid - 33 * pc;     // pc 0..13
    int t = pc / 7, vp = 25 + (pc - 7 * t);
    *reinterpret_cast<short8*>(&Fl[(t * 32 + vp) * 264 + off * 8]) = z;
  }

  // --- stage F: fp32 -> bf16, Fl[col=(t*32+vp)][cin] (non-pad cols only) ---
  {
    const int c = tid >> 1, p = tid & 1;
    const float2* src = reinterpret_cast<const float2*>(
        feature + ((size_t)(n * 256 + c) * 1024 + t0) * 25);
    for (int i = p; i < 25; i += 2) {
      float2 f = src[i];
      int j0 = 2 * i;
      {
        int j = j0;       int t = (j >= 25); int vp = j - 25 * t;
        Fl[(t * 32 + vp) * 264 + c] = f2bf(f.x);
      }
      {
        int j = j0 + 1;   int t = (j >= 25); int vp = j - 25 * t;
        Fl[(t * 32 + vp) * 264 + c] = f2bf(f.y);
      }
    }
  }

  // --- GEMM1 A-fragments from global (independent of Fl): prefetch above bar
  const int mt1 = wave & 3, nh1 = wave >> 2;
  short8 wa[8];
  #pragma unroll
  for (int ks = 0; ks < 8; ++ks)
    wa[ks] = *reinterpret_cast<const short8*>(
        WvP + (mt1 * 16 + l16) * 256 + ks * 32 + quad * 8);

  __syncthreads();                              // barrier 1: Fl ready

  // --- GEMM3 accumulators: bias + residual (read Fl while alive) ---
  f4v acc[2][4];
  #pragma unroll
  for (int mi = 0; mi < 2; ++mi) {
    const int o0 = wave * 32 + mi * 16 + quad * 4;
    float bo4[4];
    #pragma unroll
    for (int r = 0; r < 4; ++r) bo4[r] = bo[o0 + r];
    #pragma unroll
    for (int ni = 0; ni < 4; ++ni) {
      short4v fr = *reinterpret_cast<const short4v*>(
          &Fl[(ni * 16 + l16) * 264 + o0]);
      #pragma unroll
      for (int r = 0; r < 4; ++r)
        acc[mi][ni][r] = bo4[r] + bf2f((unsigned short)fr[r]);
    }
  }

  // --- GEMM1: Vm = Wv@F + bv -> Vl ---
  {
    f4v accv[2];
    #pragma unroll
    for (int ni = 0; ni < 2; ++ni) {
      #pragma unroll
      for (int r = 0; r < 4; ++r) accv[ni][r] = bv[mt1 * 16 + quad * 4 + r];
    }
    #pragma unroll
    for (int ks = 0; ks < 8; ++ks) {
      #pragma unroll
      for (int ni = 0; ni < 2; ++ni) {
        int colb = (2 * nh1 + ni) * 16 + l16;
        short8 b = *reinterpret_cast<const short8*>(
            &Fl[colb * 264 + ks * 32 + quad * 8]);
        accv[ni] = __builtin_amdgcn_mfma_f32_16x16x32_bf16(wa[ks], b, accv[ni], 0, 0, 0);
      }
    }
    #pragma unroll
    for (int ni = 0; ni < 2; ++ni) {
      int colb = (2 * nh1 + ni) * 16 + l16;
      #pragma unroll
      for (int r = 0; r < 4; ++r) {
        int c = mt1 * 16 + quad * 4 + r;
        Vl[c * 72 + colb] = f2bf(accv[ni][r]);
      }
    }
  }

  // --- GEMM2 B-fragments from attnP global (independent of Vl): prefetch ---
  const int t2 = wave >> 2, q2 = wave & 3;      // t, N-quarter (2 heads)
  short8 ab[4];
  #pragma unroll
  for (int nj = 0; nj < 4; ++nj) {
    int h = 2 * q2 + (nj >> 1), vph = nj & 1;
    ab[nj] = *reinterpret_cast<const short8*>(
        attnP + h * 1280 + (vph * 16 + l16) * 40 + quad * 8);
  }

  __syncthreads();                              // barrier 2: Vl ready, Fl dead

  // --- GEMM2: Z_cat = Vm @ [A_0|..|A_7]; write Zl[col][k=h*64+c] ---
  #pragma unroll
  for (int mi = 0; mi < 4; ++mi) {
    short8 a = *reinterpret_cast<const short8*>(
        &Vl[(mi * 16 + l16) * 72 + t2 * 32 + quad * 8]);
    #pragma unroll
    for (int nj = 0; nj < 4; ++nj) {
      f4v z = {0.f, 0.f, 0.f, 0.f};
      f4v accz = __builtin_amdgcn_mfma_f32_16x16x32_bf16(a, ab[nj], z, 0, 0, 0);
      int h = 2 * q2 + (nj >> 1), vph = nj & 1;
      int col = t2 * 32 + vph * 16 + l16;
      int k0 = h * 64 + mi * 16 + quad * 4;
      short4v zz;
      #pragma unroll
      for (int r = 0; r < 4; ++r) zz[r] = (short)f2bf(accz[r]);
      *reinterpret_cast<short4v*>(&Zl[col * 520 + k0]) = zz;
    }
  }

  // --- GEMM3 first A-chunks from global (independent of Zl): prefetch ---
  short8 af01[2][2];
  #pragma unroll
  for (int pk = 0; pk < 2; ++pk)
    #pragma unroll
    for (int mi = 0; mi < 2; ++mi)
      af01[pk][mi] = *reinterpret_cast<const short8*>(
          WoP + (wave * 32 + mi * 16 + l16) * 512 + pk * 32 + quad * 8);

  __syncthreads();                              // barrier 3: Zl ready

  // --- GEMM3: acc += Wo @ Z, K=512 in one pipelined stretch ---
  #pragma unroll
  for (int ks = 0; ks < 16; ++ks) {
    short8 bfr[4], afr[2];
    #pragma unroll
    for (int ni = 0; ni < 4; ++ni)
      bfr[ni] = *reinterpret_cast<const short8*>(
          &Zl[(ni * 16 + l16) * 520 + ks * 32 + quad * 8]);
    if (ks < 2) {
      afr[0] = af01[ks][0];
      afr[1] = af01[ks][1];
    } else {
      #pragma unroll
      for (int mi = 0; mi < 2; ++mi)
        afr[mi] = *reinterpret_cast<const short8*>(
            WoP + (wave * 32 + mi * 16 + l16) * 512 + ks * 32 + quad * 8);
    }
    #pragma unroll
    for (int mi = 0; mi < 2; ++mi) {
      #pragma unroll
      for (int ni = 0; ni < 4; ++ni)
        acc[mi][ni] =
            __builtin_amdgcn_mfma_f32_16x16x32_bf16(afr[mi], bfr[ni], acc[mi][ni], 0, 0, 0);
    }
  }

  // --- epilogue: store fp32, skip vp pads ---
  #pragma unroll
  for (int ni = 0; ni < 4; ++ni) {
    int colb = ni * 16 + l16;
    int t = colb >> 5, vp = colb & 31;
    if (vp < 25) {
      #pragma unroll
      for (int mi = 0; mi < 2; ++mi) {
        #pragma unroll
        for (int r = 0; r < 4; ++r) {
          int o = wave * 32 + mi * 16 + quad * 4 + r;
          out[((size_t)(n * 256 + o) * 1024 + (t0 + t)) * 25 + vp] = acc[mi][ni][r];
        }
      }
    }
  }
}

// ---------------------------------------------------------------------------
extern "C" void kernel_launch(void* const* d_in, const int* in_sizes, int n_in,
                              void* d_out, int out_size, void* d_ws, size_t ws_size,
                              hipStream_t stream)
{
  const float* feature = (const float*)d_in[0];
  const float* tf      = (const float*)d_in[1];
  const float* Wq      = (const float*)d_in[2];
  const float* bq      = (const float*)d_in[3];
  const float* Wk      = (const float*)d_in[4];
  const float* bk      = (const float*)d_in[5];
  const float* Wv      = (const float*)d_in[6];
  const float* bv      = (const float*)d_in[7];
  const float* Wo      = (const float*)d_in[8];
  const float* bo      = (const float*)d_in[9];
  float* out = (float*)d_out;

  unsigned short* WvP   = (unsigned short*)d_ws;        // 16384
  unsigned short* WoP   = WvP + 16384;                  // 131072
  unsigned short* attnP = WoP + 131072;                 // 10240
  float* qkP = (float*)(attnP + 10240);                 // 25600 floats

  hipLaunchKernelGGL(k_qk_conv, dim3(164), dim3(256), 0, stream,
                     tf, Wq, bq, Wk, bk, Wv, Wo, WvP, WoP, qkP);
  hipLaunchKernelGGL(k_attn, dim3(8), dim3(256), 0, stream, qkP, attnP);

  hipFuncSetAttribute(reinterpret_cast<const void*>(&k_main),
                      hipFuncAttributeMaxDynamicSharedMemorySize, 75776);
  hipLaunchKernelGGL(k_main, dim3(4096), dim3(512), 75776, stream,
                     feature, bv, bo, WvP, WoP, attnP, out);
}